// Round 1
// baseline (395.606 us; speedup 1.0000x reference)
//
#include <hip/hip_runtime.h>

// OTTT single step:
//   u_pre  = sig_tau * u + x @ W + b
//   s      = (u_pre >= 1.0)
//   u_new  = u_pre - s
//   a_hat' = sig_tau * a_hat + x
// Outputs concatenated: [s (8192) | u_new (8192) | a_hat_new (8192)], f32.
//
// Memory-bound GEMV: W = 256 MiB f32 read dominates. Split-K partials in d_ws,
// deterministic per-column reduction in a finalize kernel (no atomics so the
// spike comparison is reproducible).

#define IN_DIM   8192
#define OUT_DIM  8192
#define SIG_TAU  0.8807970779778823f   // sigmoid(2.0)
#define V_TH     1.0f

// grid.x = OUT_DIM / (4*256) = 8 column-blocks, grid.y = nchunks row-chunks.
// Each thread accumulates a float4 (4 consecutive output columns) over
// chunk_rows rows. W row stride in float4 units = OUT_DIM/4 = 2048.
__global__ __launch_bounds__(256) void gemv_partial(
    const float* __restrict__ W,
    const float* __restrict__ x,
    float* __restrict__ part,
    int chunk_rows)
{
    const int col4 = blockIdx.x * blockDim.x + threadIdx.x;   // float4 column idx
    const int row0 = blockIdx.y * chunk_rows;

    extern __shared__ float xs[];
    for (int t = threadIdx.x; t < chunk_rows; t += blockDim.x)
        xs[t] = x[row0 + t];
    __syncthreads();

    const float4* Wp = (const float4*)W + (size_t)row0 * (OUT_DIM / 4) + col4;
    float4 acc = make_float4(0.f, 0.f, 0.f, 0.f);

    #pragma unroll 4
    for (int r = 0; r < chunk_rows; ++r) {
        float4 w = Wp[(size_t)r * (OUT_DIM / 4)];
        float xv = xs[r];
        acc.x = fmaf(xv, w.x, acc.x);
        acc.y = fmaf(xv, w.y, acc.y);
        acc.z = fmaf(xv, w.z, acc.z);
        acc.w = fmaf(xv, w.w, acc.w);
    }

    ((float4*)part)[(size_t)blockIdx.y * (OUT_DIM / 4) + col4] = acc;
}

__global__ __launch_bounds__(256) void finalize_lif(
    const float* __restrict__ part,
    const float* __restrict__ b,
    const float* __restrict__ u,
    const float* __restrict__ a_hat,
    const float* __restrict__ x,
    float* __restrict__ out,
    int nchunks)
{
    const int j = blockIdx.x * blockDim.x + threadIdx.x;
    if (j >= OUT_DIM) return;

    float sum = 0.f;
    for (int c = 0; c < nchunks; ++c)
        sum += part[(size_t)c * OUT_DIM + j];

    const float u_pre = fmaf(SIG_TAU, u[j], sum + b[j]);
    const float s = (u_pre >= V_TH) ? 1.0f : 0.0f;

    out[j]               = s;
    out[OUT_DIM + j]     = u_pre - s * V_TH;
    out[2 * OUT_DIM + j] = fmaf(SIG_TAU, a_hat[j], x[j]);
}

extern "C" void kernel_launch(void* const* d_in, const int* in_sizes, int n_in,
                              void* d_out, int out_size, void* d_ws, size_t ws_size,
                              hipStream_t stream)
{
    const float* W     = (const float*)d_in[0];
    const float* b     = (const float*)d_in[1];
    const float* u     = (const float*)d_in[2];
    const float* a_hat = (const float*)d_in[3];
    const float* x     = (const float*)d_in[4];
    float* out  = (float*)d_out;
    float* part = (float*)d_ws;

    // 128 row-chunks -> 1024 blocks (4 blocks/CU) for HBM saturation; shrink
    // if the workspace can't hold nchunks * OUT_DIM partial floats.
    int nchunks = 128;
    while (nchunks > 1 && (size_t)nchunks * OUT_DIM * sizeof(float) > ws_size)
        nchunks >>= 1;
    const int chunk_rows = IN_DIM / nchunks;

    dim3 grid(OUT_DIM / (4 * 256), nchunks);
    gemv_partial<<<grid, 256, chunk_rows * sizeof(float), stream>>>(W, x, part, chunk_rows);

    finalize_lif<<<OUT_DIM / 256, 256, 0, stream>>>(part, b, u, a_hat, x, out, nchunks);
}

// Round 2
// 378.880 us; speedup vs baseline: 1.0441x; 1.0441x over previous
//
#include <hip/hip_runtime.h>

// OTTT single step:
//   u_pre  = sig_tau * u + x @ W + b
//   s      = (u_pre >= 1.0)
//   u_new  = u_pre - s
//   a_hat' = sig_tau * a_hat + x
// Outputs concatenated: [s (8192) | u_new (8192) | a_hat_new (8192)], f32.
//
// HBM-bound GEMV: W = 256 MiB f32 read dominates (~43 us floor at 6.3 TB/s).
// Split-K partials in d_ws, deterministic per-column reduction in finalize
// (no atomics so the spike comparison is reproducible).
//
// R1 change: compile-time CHUNK_ROWS=32 fully unrolled (32 independent
// dwordx4 loads/thread for MLP), 2048 blocks, launch_bounds(256,4).

#define IN_DIM     8192
#define OUT_DIM    8192
#define SIG_TAU    0.8807970779778823f   // sigmoid(2.0)
#define V_TH       1.0f
#define CHUNK_ROWS 32
#define NCHUNKS    (IN_DIM / CHUNK_ROWS)   // 256

// grid = (8, 256). Each thread owns 4 consecutive output columns (float4)
// and accumulates over its chunk's 32 rows. W row stride = 2048 float4s.
__global__ __launch_bounds__(256, 4) void gemv_partial_u32(
    const float* __restrict__ W,
    const float* __restrict__ x,
    float* __restrict__ part)
{
    const int col4 = blockIdx.x * 256 + threadIdx.x;      // float4 column idx
    const int row0 = blockIdx.y * CHUNK_ROWS;

    __shared__ float xs[CHUNK_ROWS];
    if (threadIdx.x < CHUNK_ROWS) xs[threadIdx.x] = x[row0 + threadIdx.x];
    __syncthreads();

    const float4* Wp = (const float4*)W + (size_t)row0 * (OUT_DIM / 4) + col4;
    float4 acc = make_float4(0.f, 0.f, 0.f, 0.f);

    #pragma unroll
    for (int r = 0; r < CHUNK_ROWS; ++r) {
        float4 w = Wp[(size_t)r * (OUT_DIM / 4)];
        const float xv = xs[r];
        acc.x = fmaf(xv, w.x, acc.x);
        acc.y = fmaf(xv, w.y, acc.y);
        acc.z = fmaf(xv, w.z, acc.z);
        acc.w = fmaf(xv, w.w, acc.w);
    }

    ((float4*)part)[(size_t)blockIdx.y * (OUT_DIM / 4) + col4] = acc;
}

// Fallback when ws_size can't hold NCHUNKS*OUT_DIM partials (runtime rows).
__global__ __launch_bounds__(256) void gemv_partial_gen(
    const float* __restrict__ W,
    const float* __restrict__ x,
    float* __restrict__ part,
    int chunk_rows)
{
    const int col4 = blockIdx.x * 256 + threadIdx.x;
    const int row0 = blockIdx.y * chunk_rows;

    extern __shared__ float xsg[];
    for (int t = threadIdx.x; t < chunk_rows; t += 256)
        xsg[t] = x[row0 + t];
    __syncthreads();

    const float4* Wp = (const float4*)W + (size_t)row0 * (OUT_DIM / 4) + col4;
    float4 acc = make_float4(0.f, 0.f, 0.f, 0.f);

    #pragma unroll 8
    for (int r = 0; r < chunk_rows; ++r) {
        float4 w = Wp[(size_t)r * (OUT_DIM / 4)];
        const float xv = xsg[r];
        acc.x = fmaf(xv, w.x, acc.x);
        acc.y = fmaf(xv, w.y, acc.y);
        acc.z = fmaf(xv, w.z, acc.z);
        acc.w = fmaf(xv, w.w, acc.w);
    }

    ((float4*)part)[(size_t)blockIdx.y * (OUT_DIM / 4) + col4] = acc;
}

__global__ __launch_bounds__(256) void finalize_lif(
    const float* __restrict__ part,
    const float* __restrict__ b,
    const float* __restrict__ u,
    const float* __restrict__ a_hat,
    const float* __restrict__ x,
    float* __restrict__ out,
    int nchunks)
{
    const int j = blockIdx.x * 256 + threadIdx.x;
    if (j >= OUT_DIM) return;

    float sum = 0.f;
    #pragma unroll 8
    for (int c = 0; c < nchunks; ++c)
        sum += part[(size_t)c * OUT_DIM + j];

    const float u_pre = fmaf(SIG_TAU, u[j], sum + b[j]);
    const float s = (u_pre >= V_TH) ? 1.0f : 0.0f;

    out[j]               = s;
    out[OUT_DIM + j]     = u_pre - s * V_TH;
    out[2 * OUT_DIM + j] = fmaf(SIG_TAU, a_hat[j], x[j]);
}

extern "C" void kernel_launch(void* const* d_in, const int* in_sizes, int n_in,
                              void* d_out, int out_size, void* d_ws, size_t ws_size,
                              hipStream_t stream)
{
    const float* W     = (const float*)d_in[0];
    const float* b     = (const float*)d_in[1];
    const float* u     = (const float*)d_in[2];
    const float* a_hat = (const float*)d_in[3];
    const float* x     = (const float*)d_in[4];
    float* out  = (float*)d_out;
    float* part = (float*)d_ws;

    if ((size_t)NCHUNKS * OUT_DIM * sizeof(float) <= ws_size) {
        dim3 grid(OUT_DIM / (4 * 256), NCHUNKS);
        gemv_partial_u32<<<grid, 256, 0, stream>>>(W, x, part);
        finalize_lif<<<OUT_DIM / 256, 256, 0, stream>>>(part, b, u, a_hat, x, out, NCHUNKS);
    } else {
        int nchunks = 128;
        while (nchunks > 1 && (size_t)nchunks * OUT_DIM * sizeof(float) > ws_size)
            nchunks >>= 1;
        const int chunk_rows = IN_DIM / nchunks;
        dim3 grid(OUT_DIM / (4 * 256), nchunks);
        gemv_partial_gen<<<grid, 256, chunk_rows * sizeof(float), stream>>>(W, x, part, chunk_rows);
        finalize_lif<<<OUT_DIM / 256, 256, 0, stream>>>(part, b, u, a_hat, x, out, nchunks);
    }
}